// Round 1
// baseline (741.535 us; speedup 1.0000x reference)
//
#include <hip/hip_runtime.h>
#include <hip/hip_bf16.h>

// Problem constants (from reference)
#define BB 512
#define NN 1024
#define MM 128
#define OUTD 256
#define MOLD 256
#define IND 512
#define RROWS 65536     // BB * MM

typedef float f32x4 __attribute__((ext_vector_type(4)));
typedef short s16x8 __attribute__((ext_vector_type(8)));
typedef __bf16 bf16x8 __attribute__((ext_vector_type(8)));

#define AS_GLOBAL const __attribute__((address_space(1))) void
#define AS_LDS __attribute__((address_space(3))) void

__device__ __forceinline__ unsigned short f2bf(float f) {
    unsigned int u = __builtin_bit_cast(unsigned int, f);
    u = (u + 0x7fffu + ((u >> 16) & 1u)) >> 16;
    return (unsigned short)u;
}

// ---------------- prep: W2 (full) and W1a = W1[:, :256] fp32 -> bf16 -------
// grid: 256 blocks x 256 threads. W2: 65536 float4. W1a: 32768 float4.
__global__ __launch_bounds__(256) void prep_weights(
    const float* __restrict__ W1, const float* __restrict__ W2,
    unsigned short* __restrict__ W1ab, unsigned short* __restrict__ W2b) {
    int i = blockIdx.x * 256 + threadIdx.x;  // [0, 65536)
    float4 b = ((const float4*)W2)[i];
    ushort4 pb;
    pb.x = f2bf(b.x); pb.y = f2bf(b.y); pb.z = f2bf(b.z); pb.w = f2bf(b.w);
    ((ushort4*)W2b)[i] = pb;
    if (i < 32768) {
        int row = i >> 6, c4 = i & 63;   // row < 512, c4*4 < 256
        float4 a = ((const float4*)(W1 + (size_t)row * 512))[c4];
        ushort4 pa;
        pa.x = f2bf(a.x); pa.y = f2bf(a.y); pa.z = f2bf(a.z); pa.w = f2bf(a.w);
        ((ushort4*)(W1ab + (size_t)row * 256))[c4] = pa;
    }
}

// ---------------- C1[b,n] = b1[n] + dot(molvec[b,:], W1[n, 256:512]) -------
// fp32 exact (more accurate than the old bf16 molvec path).
// grid: 512 blocks (one per b) x 256 threads; each thread does n = t, t+256.
__global__ __launch_bounds__(256) void c1_kernel(
    const float* __restrict__ mol, const float* __restrict__ W1,
    const float* __restrict__ b1, float* __restrict__ C1) {
    __shared__ float ms[MOLD];
    const int b = blockIdx.x, t = threadIdx.x;
    ms[t] = mol[(size_t)b * MOLD + t];
    __syncthreads();
#pragma unroll
    for (int h = 0; h < 2; ++h) {
        const int n = h * 256 + t;
        const f32x4* w = (const f32x4*)(W1 + (size_t)n * 512 + 256);
        float acc = 0.f;
#pragma unroll 4
        for (int k4 = 0; k4 < 64; ++k4) {
            f32x4 wv = w[k4];
            acc += wv[0] * ms[k4 * 4 + 0];
            acc += wv[1] * ms[k4 * 4 + 1];
            acc += wv[2] * ms[k4 * 4 + 2];
            acc += wv[3] * ms[k4 * 4 + 3];
        }
        C1[(size_t)b * IND + n] = acc + b1[n];
    }
}

// ---------------- gather: Ag[r, :256] = bf16(X[b, idx_M[b,m], :]) ----------
// r = b*128 + m. One wave covers 2 rows (32 lanes x 8 floats = 1KB/row).
// grid: 8192 blocks x 256 threads (8 rows per block).
__global__ __launch_bounds__(256) void gather_kernel(
    const float* __restrict__ X, const int* __restrict__ idxp,
    unsigned short* __restrict__ Ag) {
    const int t = threadIdx.x;
    const int r = blockIdx.x * 8 + (t >> 5);   // [0, 65536)
    const int l = t & 31;
    const int b = r >> 7;
    const int idx = idxp[r];                   // idxp[b*128 + m] == idxp[r]
    const float* src = X + ((size_t)b * NN + idx) * OUTD + l * 8;
    float4 v0 = ((const float4*)src)[0];
    float4 v1 = ((const float4*)src)[1];
    ushort4 p0, p1;
    p0.x = f2bf(v0.x); p0.y = f2bf(v0.y); p0.z = f2bf(v0.z); p0.w = f2bf(v0.w);
    p1.x = f2bf(v1.x); p1.y = f2bf(v1.y); p1.z = f2bf(v1.z); p1.w = f2bf(v1.w);
    unsigned short* dst = Ag + (size_t)r * OUTD + l * 8;
    ((ushort4*)dst)[0] = p0;
    ((ushort4*)dst)[1] = p1;
}

// ---------------- GEMM1: H = relu(Ag @ W1a^T + C1[b]), K=256 --------------
// Pure streaming (global_load_lds both operands) — same skeleton as gemm2.
// grid: (512 row-blocks == b, 4 n-tiles), 256 threads.
__global__ __launch_bounds__(256) void gemm1_kernel(
    const unsigned short* __restrict__ Ag, const unsigned short* __restrict__ W1ab,
    const float* __restrict__ C1, unsigned short* __restrict__ H) {
    __shared__ __align__(16) unsigned short Asm[128 * 32];
    __shared__ __align__(16) unsigned short Bsm[128 * 32];

    const int t = threadIdx.x;
    const int lane = t & 63, w = t >> 6;
    const int b = blockIdx.x;
    const int row0 = b * 128;
    const int n0 = blockIdx.y * 128;
    const int wr = (w >> 1) * 64, wc = (w & 1) * 64;
    const int lr = lane & 15, quad = lane >> 4;

    f32x4 acc[4][4];
#pragma unroll
    for (int mi = 0; mi < 4; ++mi)
#pragma unroll
        for (int ni = 0; ni < 4; ++ni) acc[mi][ni] = {0.f, 0.f, 0.f, 0.f};

    for (int ki = 0; ki < 8; ++ki) {   // K = 256
        const int kt = ki * 32;
#pragma unroll
        for (int j = 0; j < 2; ++j) {
            const int cidx = j * 4 + w;             // chunk: 64 lanes x 16B
            const int s = cidx * 64 + lane;         // row = s>>2, seg = s&3
            const unsigned short* ga = Ag + (size_t)(row0 + (s >> 2)) * OUTD + kt + (s & 3) * 8;
            __builtin_amdgcn_global_load_lds((AS_GLOBAL*)ga, (AS_LDS*)(Asm + cidx * 512), 16, 0, 0);
            const unsigned short* gb = W1ab + (size_t)(n0 + (s >> 2)) * OUTD + kt + (s & 3) * 8;
            __builtin_amdgcn_global_load_lds((AS_GLOBAL*)gb, (AS_LDS*)(Bsm + cidx * 512), 16, 0, 0);
        }
        __syncthreads();
        s16x8 af[4], bfr[4];
#pragma unroll
        for (int i = 0; i < 4; ++i)
            af[i] = *(const s16x8*)&Asm[(wr + i * 16 + lr) * 32 + quad * 8];
#pragma unroll
        for (int i = 0; i < 4; ++i)
            bfr[i] = *(const s16x8*)&Bsm[(wc + i * 16 + lr) * 32 + quad * 8];
#pragma unroll
        for (int mi = 0; mi < 4; ++mi)
#pragma unroll
            for (int ni = 0; ni < 4; ++ni)
                acc[mi][ni] = __builtin_amdgcn_mfma_f32_16x16x32_bf16(
                    __builtin_bit_cast(bf16x8, af[mi]),
                    __builtin_bit_cast(bf16x8, bfr[ni]), acc[mi][ni], 0, 0, 0);
        __syncthreads();
    }

    // epilogue: + C1[b, n], relu, bf16 store to H
    float bias[4];
#pragma unroll
    for (int ni = 0; ni < 4; ++ni) bias[ni] = C1[(size_t)b * IND + n0 + wc + ni * 16 + lr];
#pragma unroll
    for (int mi = 0; mi < 4; ++mi) {
#pragma unroll
        for (int ni = 0; ni < 4; ++ni) {
            const int gcol = n0 + wc + ni * 16 + lr;
#pragma unroll
            for (int rr = 0; rr < 4; ++rr) {
                const int grow = row0 + wr + mi * 16 + quad * 4 + rr;
                float v = acc[mi][ni][rr] + bias[ni];
                v = v > 0.f ? v : 0.f;
                H[(size_t)grow * IND + gcol] = f2bf(v);
            }
        }
    }
}

// ---------------- GEMM2: out = H @ W2^T + b2 (fp32 out), K=512 ------------
__global__ __launch_bounds__(256) void gemm2_kernel(
    const unsigned short* __restrict__ Hb, const unsigned short* __restrict__ W2b,
    const float* __restrict__ b2, float* __restrict__ out) {
    __shared__ __align__(16) unsigned short Asm[128 * 32];
    __shared__ __align__(16) unsigned short Bsm[128 * 32];

    const int t = threadIdx.x;
    const int lane = t & 63, w = t >> 6;
    const int row0 = blockIdx.x * 128;
    const int n0 = blockIdx.y * 128;
    const int wr = (w >> 1) * 64, wc = (w & 1) * 64;
    const int lr = lane & 15, quad = lane >> 4;

    f32x4 acc[4][4];
#pragma unroll
    for (int mi = 0; mi < 4; ++mi)
#pragma unroll
        for (int ni = 0; ni < 4; ++ni) acc[mi][ni] = {0.f, 0.f, 0.f, 0.f};

    for (int ki = 0; ki < 16; ++ki) {
        const int kt = ki * 32;
#pragma unroll
        for (int j = 0; j < 2; ++j) {
            const int cidx = j * 4 + w;
            const int s = cidx * 64 + lane;
            const unsigned short* ga = Hb + (size_t)(row0 + (s >> 2)) * IND + kt + (s & 3) * 8;
            __builtin_amdgcn_global_load_lds((AS_GLOBAL*)ga, (AS_LDS*)(Asm + cidx * 512), 16, 0, 0);
            const unsigned short* gb = W2b + (size_t)(n0 + (s >> 2)) * IND + kt + (s & 3) * 8;
            __builtin_amdgcn_global_load_lds((AS_GLOBAL*)gb, (AS_LDS*)(Bsm + cidx * 512), 16, 0, 0);
        }
        __syncthreads();
        s16x8 af[4], bfr[4];
#pragma unroll
        for (int i = 0; i < 4; ++i)
            af[i] = *(const s16x8*)&Asm[(wr + i * 16 + lr) * 32 + quad * 8];
#pragma unroll
        for (int i = 0; i < 4; ++i)
            bfr[i] = *(const s16x8*)&Bsm[(wc + i * 16 + lr) * 32 + quad * 8];
#pragma unroll
        for (int mi = 0; mi < 4; ++mi)
#pragma unroll
            for (int ni = 0; ni < 4; ++ni)
                acc[mi][ni] = __builtin_amdgcn_mfma_f32_16x16x32_bf16(
                    __builtin_bit_cast(bf16x8, af[mi]),
                    __builtin_bit_cast(bf16x8, bfr[ni]), acc[mi][ni], 0, 0, 0);
        __syncthreads();
    }

    float bias[4];
#pragma unroll
    for (int ni = 0; ni < 4; ++ni) bias[ni] = b2[n0 + wc + ni * 16 + lr];
#pragma unroll
    for (int mi = 0; mi < 4; ++mi) {
#pragma unroll
        for (int ni = 0; ni < 4; ++ni) {
            const int gcol = n0 + wc + ni * 16 + lr;
#pragma unroll
            for (int rr = 0; rr < 4; ++rr) {
                const int grow = row0 + wr + mi * 16 + quad * 4 + rr;
                out[(size_t)grow * IND + gcol] = acc[mi][ni][rr] + bias[ni];
            }
        }
    }
}

extern "C" void kernel_launch(void* const* d_in, const int* in_sizes, int n_in,
                              void* d_out, int out_size, void* d_ws, size_t ws_size,
                              hipStream_t stream) {
    const float* X = (const float*)d_in[0];       // [512,1024,256]
    const float* mol = (const float*)d_in[1];     // [512,256]
    const int* idx = (const int*)d_in[2];         // [512,128] (int32 — JAX x64 off)
    const float* W1 = (const float*)d_in[3];      // [512,512]
    const float* b1 = (const float*)d_in[4];      // [512]
    const float* W2 = (const float*)d_in[5];      // [512,512]
    const float* b2 = (const float*)d_in[6];      // [512]
    float* out = (float*)d_out;                   // [65536,512]

    // workspace: W1a bf16 (256KiB) | W2 bf16 (512KiB) | C1 f32 (1MiB)
    //          | Ag bf16 (32MiB)   | H bf16 (64MiB)          total ~97.75MiB
    unsigned short* W1ab = (unsigned short*)d_ws;
    unsigned short* W2b = W1ab + 512 * 256;
    float* C1 = (float*)(W2b + 512 * 512);
    unsigned short* Ag = (unsigned short*)(C1 + 512 * 512);
    unsigned short* H = Ag + (size_t)RROWS * OUTD;

    prep_weights<<<256, 256, 0, stream>>>(W1, W2, W1ab, W2b);
    c1_kernel<<<512, 256, 0, stream>>>(mol, W1, b1, C1);
    gather_kernel<<<8192, 256, 0, stream>>>(X, idx, Ag);
    gemm1_kernel<<<dim3(BB, IND / 128), 256, 0, stream>>>(Ag, W1ab, C1, H);
    gemm2_kernel<<<dim3(RROWS / 128, IND / 128), 256, 0, stream>>>(H, W2b, b2, out);
}

// Round 2
// 727.991 us; speedup vs baseline: 1.0186x; 1.0186x over previous
//
#include <hip/hip_runtime.h>
#include <hip/hip_bf16.h>

// Problem constants (from reference)
#define BB 512
#define NN 1024
#define MM 128
#define OUTD 256
#define MOLD 256
#define IND 512
#define RROWS 65536     // BB * MM

typedef float f32x4 __attribute__((ext_vector_type(4)));
typedef short s16x8 __attribute__((ext_vector_type(8)));
typedef __bf16 bf16x8 __attribute__((ext_vector_type(8)));

#define AS_GLOBAL const __attribute__((address_space(1))) void
#define AS_LDS __attribute__((address_space(3))) void

__device__ __forceinline__ unsigned short f2bf(float f) {
    unsigned int u = __builtin_bit_cast(unsigned int, f);
    u = (u + 0x7fffu + ((u >> 16) & 1u)) >> 16;
    return (unsigned short)u;
}

// ---------------- prep: W2 (full) and W1a = W1[:, :256] fp32 -> bf16 -------
// grid: 256 blocks x 256 threads. W2: 65536 float4. W1a: 32768 float4.
__global__ __launch_bounds__(256) void prep_weights(
    const float* __restrict__ W1, const float* __restrict__ W2,
    unsigned short* __restrict__ W1ab, unsigned short* __restrict__ W2b) {
    int i = blockIdx.x * 256 + threadIdx.x;  // [0, 65536)
    float4 b = ((const float4*)W2)[i];
    ushort4 pb;
    pb.x = f2bf(b.x); pb.y = f2bf(b.y); pb.z = f2bf(b.z); pb.w = f2bf(b.w);
    ((ushort4*)W2b)[i] = pb;
    if (i < 32768) {
        int row = i >> 6, c4 = i & 63;   // row < 512, c4*4 < 256
        float4 a = ((const float4*)(W1 + (size_t)row * 512))[c4];
        ushort4 pa;
        pa.x = f2bf(a.x); pa.y = f2bf(a.y); pa.z = f2bf(a.z); pa.w = f2bf(a.w);
        ((ushort4*)(W1ab + (size_t)row * 256))[c4] = pa;
    }
}

// ---------------- C1[b,n] = b1[n] + dot(molvec[b,:], W1[n, 256:512]) -------
// fp32 exact. grid: 512 blocks (one per b) x 256 threads; n = t, t+256.
__global__ __launch_bounds__(256) void c1_kernel(
    const float* __restrict__ mol, const float* __restrict__ W1,
    const float* __restrict__ b1, float* __restrict__ C1) {
    __shared__ float ms[MOLD];
    const int b = blockIdx.x, t = threadIdx.x;
    ms[t] = mol[(size_t)b * MOLD + t];
    __syncthreads();
#pragma unroll
    for (int h = 0; h < 2; ++h) {
        const int n = h * 256 + t;
        const f32x4* w = (const f32x4*)(W1 + (size_t)n * 512 + 256);
        float acc = 0.f;
#pragma unroll 4
        for (int k4 = 0; k4 < 64; ++k4) {
            f32x4 wv = w[k4];
            acc += wv[0] * ms[k4 * 4 + 0];
            acc += wv[1] * ms[k4 * 4 + 1];
            acc += wv[2] * ms[k4 * 4 + 2];
            acc += wv[3] * ms[k4 * 4 + 3];
        }
        C1[(size_t)b * IND + n] = acc + b1[n];
    }
}

// ---------------- GEMM1 fused: H = relu(gather(X) @ W1a^T + C1[b]) --------
// One block per b. Gathered A-tile (128 x 256 bf16, 64KB) staged ONCE into
// LDS with k-unit XOR swizzle (slot = u ^ (row&7)) to kill the 512B-stride
// bank conflict on fragment reads; reused across all 4 n-tiles. W1ab
// streamed via global_load_lds (linear LDS, m97 pattern). 72KB LDS ->
// 2 blocks/CU.
__global__ __launch_bounds__(256) void gemm1_fused(
    const float* __restrict__ X, const int* __restrict__ idxp,
    const unsigned short* __restrict__ W1ab, const float* __restrict__ C1,
    unsigned short* __restrict__ H) {
    __shared__ __align__(16) unsigned short A1[128 * 256];  // 64KB, swizzled
    __shared__ __align__(16) unsigned short Bsm[128 * 32];  // 8KB, linear

    const int t = threadIdx.x;
    const int lane = t & 63, w = t >> 6;
    const int b = blockIdx.x;
    const int row0 = b * 128;
    const int wr = (w >> 1) * 64, wc = (w & 1) * 64;
    const int lr = lane & 15, quad = lane >> 4;

    // ---- phase 0: gather 128 rows of X, cvt to bf16, swizzled LDS store --
    // 32 threads per row (8 floats each); wave = 2 rows x 512B contiguous
    // (permuted within row) -> conflict-free ds_write_b128.
#pragma unroll 4
    for (int p = 0; p < 16; ++p) {
        const int r = p * 8 + (t >> 5);          // row in [0,128)
        const int c = t & 31;                    // 16B k-unit in [0,32)
        const int idxg = idxp[b * MM + r];
        const float* src = X + ((size_t)b * NN + idxg) * OUTD + c * 8;
        float4 v0 = ((const float4*)src)[0];
        float4 v1 = ((const float4*)src)[1];
        ushort4 p0, p1;
        p0.x = f2bf(v0.x); p0.y = f2bf(v0.y); p0.z = f2bf(v0.z); p0.w = f2bf(v0.w);
        p1.x = f2bf(v1.x); p1.y = f2bf(v1.y); p1.z = f2bf(v1.z); p1.w = f2bf(v1.w);
        const int slot = c ^ (r & 7);            // XOR swizzle (bijective/row)
        unsigned short* dst = &A1[r * 256 + slot * 8];
        ((ushort4*)dst)[0] = p0;
        ((ushort4*)dst)[1] = p1;
    }
    __syncthreads();

    // ---- phase 1: 4 n-tiles x 8 K-iters -------------------------------
    for (int nt = 0; nt < 4; ++nt) {
        const int n0 = nt * 128;
        f32x4 acc[4][4];
#pragma unroll
        for (int mi = 0; mi < 4; ++mi)
#pragma unroll
            for (int ni = 0; ni < 4; ++ni) acc[mi][ni] = {0.f, 0.f, 0.f, 0.f};

        for (int ki = 0; ki < 8; ++ki) {   // K = 256
            const int kt = ki * 32;
#pragma unroll
            for (int j = 0; j < 2; ++j) {
                const int cidx = j * 4 + w;      // 8 chunks of 64 lanes x 16B
                const int s = cidx * 64 + lane;  // row = s>>2, seg = s&3
                const unsigned short* gb =
                    W1ab + (size_t)(n0 + (s >> 2)) * OUTD + kt + (s & 3) * 8;
                __builtin_amdgcn_global_load_lds((AS_GLOBAL*)gb,
                                                 (AS_LDS*)(Bsm + cidx * 512), 16, 0, 0);
            }
            __syncthreads();
            s16x8 af[4], bfr[4];
#pragma unroll
            for (int i = 0; i < 4; ++i) {
                const int ra = wr + i * 16 + lr;
                const int sa = ((ki << 2) + quad) ^ (lr & 7);  // unswizzle
                af[i] = *(const s16x8*)&A1[ra * 256 + sa * 8];
            }
#pragma unroll
            for (int i = 0; i < 4; ++i)
                bfr[i] = *(const s16x8*)&Bsm[(wc + i * 16 + lr) * 32 + quad * 8];
#pragma unroll
            for (int mi = 0; mi < 4; ++mi)
#pragma unroll
                for (int ni = 0; ni < 4; ++ni)
                    acc[mi][ni] = __builtin_amdgcn_mfma_f32_16x16x32_bf16(
                        __builtin_bit_cast(bf16x8, af[mi]),
                        __builtin_bit_cast(bf16x8, bfr[ni]), acc[mi][ni], 0, 0, 0);
            __syncthreads();
        }

        // epilogue: + C1[b, n], relu, bf16 store to H
        float bias[4];
#pragma unroll
        for (int ni = 0; ni < 4; ++ni)
            bias[ni] = C1[(size_t)b * IND + n0 + wc + ni * 16 + lr];
#pragma unroll
        for (int mi = 0; mi < 4; ++mi) {
#pragma unroll
            for (int ni = 0; ni < 4; ++ni) {
                const int gcol = n0 + wc + ni * 16 + lr;
#pragma unroll
                for (int rr = 0; rr < 4; ++rr) {
                    const int grow = row0 + wr + mi * 16 + quad * 4 + rr;
                    float v = acc[mi][ni][rr] + bias[ni];
                    v = v > 0.f ? v : 0.f;
                    H[(size_t)grow * IND + gcol] = f2bf(v);
                }
            }
        }
    }
}

// ---------------- GEMM2: out = H @ W2^T + b2 (fp32 out), K=512 ------------
__global__ __launch_bounds__(256) void gemm2_kernel(
    const unsigned short* __restrict__ Hb, const unsigned short* __restrict__ W2b,
    const float* __restrict__ b2, float* __restrict__ out) {
    __shared__ __align__(16) unsigned short Asm[128 * 32];
    __shared__ __align__(16) unsigned short Bsm[128 * 32];

    const int t = threadIdx.x;
    const int lane = t & 63, w = t >> 6;
    const int row0 = blockIdx.x * 128;
    const int n0 = blockIdx.y * 128;
    const int wr = (w >> 1) * 64, wc = (w & 1) * 64;
    const int lr = lane & 15, quad = lane >> 4;

    f32x4 acc[4][4];
#pragma unroll
    for (int mi = 0; mi < 4; ++mi)
#pragma unroll
        for (int ni = 0; ni < 4; ++ni) acc[mi][ni] = {0.f, 0.f, 0.f, 0.f};

    for (int ki = 0; ki < 16; ++ki) {
        const int kt = ki * 32;
#pragma unroll
        for (int j = 0; j < 2; ++j) {
            const int cidx = j * 4 + w;
            const int s = cidx * 64 + lane;
            const unsigned short* ga = Hb + (size_t)(row0 + (s >> 2)) * IND + kt + (s & 3) * 8;
            __builtin_amdgcn_global_load_lds((AS_GLOBAL*)ga, (AS_LDS*)(Asm + cidx * 512), 16, 0, 0);
            const unsigned short* gb = W2b + (size_t)(n0 + (s >> 2)) * IND + kt + (s & 3) * 8;
            __builtin_amdgcn_global_load_lds((AS_GLOBAL*)gb, (AS_LDS*)(Bsm + cidx * 512), 16, 0, 0);
        }
        __syncthreads();
        s16x8 af[4], bfr[4];
#pragma unroll
        for (int i = 0; i < 4; ++i)
            af[i] = *(const s16x8*)&Asm[(wr + i * 16 + lr) * 32 + quad * 8];
#pragma unroll
        for (int i = 0; i < 4; ++i)
            bfr[i] = *(const s16x8*)&Bsm[(wc + i * 16 + lr) * 32 + quad * 8];
#pragma unroll
        for (int mi = 0; mi < 4; ++mi)
#pragma unroll
            for (int ni = 0; ni < 4; ++ni)
                acc[mi][ni] = __builtin_amdgcn_mfma_f32_16x16x32_bf16(
                    __builtin_bit_cast(bf16x8, af[mi]),
                    __builtin_bit_cast(bf16x8, bfr[ni]), acc[mi][ni], 0, 0, 0);
        __syncthreads();
    }

    float bias[4];
#pragma unroll
    for (int ni = 0; ni < 4; ++ni) bias[ni] = b2[n0 + wc + ni * 16 + lr];
#pragma unroll
    for (int mi = 0; mi < 4; ++mi) {
#pragma unroll
        for (int ni = 0; ni < 4; ++ni) {
            const int gcol = n0 + wc + ni * 16 + lr;
#pragma unroll
            for (int rr = 0; rr < 4; ++rr) {
                const int grow = row0 + wr + mi * 16 + quad * 4 + rr;
                out[(size_t)grow * IND + gcol] = acc[mi][ni][rr] + bias[ni];
            }
        }
    }
}

extern "C" void kernel_launch(void* const* d_in, const int* in_sizes, int n_in,
                              void* d_out, int out_size, void* d_ws, size_t ws_size,
                              hipStream_t stream) {
    const float* X = (const float*)d_in[0];       // [512,1024,256]
    const float* mol = (const float*)d_in[1];     // [512,256]
    const int* idx = (const int*)d_in[2];         // [512,128]
    const float* W1 = (const float*)d_in[3];      // [512,512]
    const float* b1 = (const float*)d_in[4];      // [512]
    const float* W2 = (const float*)d_in[5];      // [512,512]
    const float* b2 = (const float*)d_in[6];      // [512]
    float* out = (float*)d_out;                   // [65536,512]

    // workspace: W1a bf16 (256KiB) | W2 bf16 (512KiB) | C1 f32 (1MiB)
    //          | H bf16 (64MiB)                         total ~65.75MiB
    unsigned short* W1ab = (unsigned short*)d_ws;
    unsigned short* W2b = W1ab + 512 * 256;
    float* C1 = (float*)(W2b + 512 * 512);
    unsigned short* H = (unsigned short*)(C1 + 512 * 512);

    prep_weights<<<256, 256, 0, stream>>>(W1, W2, W1ab, W2b);
    c1_kernel<<<512, 256, 0, stream>>>(mol, W1, b1, C1);
    gemm1_fused<<<BB, 256, 0, stream>>>(X, idx, W1ab, C1, H);
    gemm2_kernel<<<dim3(RROWS / 128, IND / 128), 256, 0, stream>>>(H, W2b, b2, out);
}